// Round 1
// baseline (362.881 us; speedup 1.0000x reference)
//
#include <hip/hip_runtime.h>
#include <math.h>

#define BATCH 8
#define SEQ   2048
#define CDIM  1024
#define HSD   64
#define NROWS (BATCH * SEQ)
#define BQ    32
#define BK    64

// ---------------- Kernel 1: fused QKV projection ----------------
// X:(16384,1024) fp32, Wq/Wk/Wv:(1024,64) -> Q,K,V:(16384,64) fp32 in ws.
// Block: 256 thr, 32 rows x 192 cols (q|k|v fused: X read once), BK=32.
__global__ __launch_bounds__(256) void qkv_proj_kernel(
    const float* __restrict__ X,
    const float* __restrict__ Wq, const float* __restrict__ Wk,
    const float* __restrict__ Wv,
    float* __restrict__ Q, float* __restrict__ K, float* __restrict__ V)
{
    __shared__ float Xs[32][36];    // +4 pad keeps float4 alignment
    __shared__ float Ws[32][196];   // cols 0..63=q, 64..127=k, 128..191=v
    const int t  = threadIdx.x;
    const int m0 = blockIdx.x * 32;
    const int ty = t >> 5;          // 0..7  -> rows ty*4+i
    const int tx = t & 31;          // 0..31 -> cols tx*6+j

    float acc[4][6];
#pragma unroll
    for (int i = 0; i < 4; ++i)
#pragma unroll
        for (int j = 0; j < 6; ++j) acc[i][j] = 0.f;

    const int xrow = t >> 3, xc4 = (t & 7) << 2;

    for (int k0 = 0; k0 < CDIM; k0 += 32) {
        // global loads into regs first (overlap with previous compute)
        float4 xv = *(const float4*)&X[(size_t)(m0 + xrow) * CDIM + k0 + xc4];
        float4 wv[6];
#pragma unroll
        for (int u = 0; u < 6; ++u) {
            int idx = t + u * 256;          // 0..1535 float4s of 32x192 tile
            int k = idx / 48, c4 = idx % 48;
            const float* src = (c4 < 16) ? Wq : (c4 < 32) ? Wk : Wv;
            wv[u] = *(const float4*)&src[(size_t)(k0 + k) * HSD + ((c4 & 15) << 2)];
        }
        __syncthreads();                    // previous readers done
        *(float4*)&Xs[xrow][xc4] = xv;
#pragma unroll
        for (int u = 0; u < 6; ++u) {
            int idx = t + u * 256;
            int k = idx / 48, c4 = idx % 48;
            *(float4*)&Ws[k][c4 << 2] = wv[u];
        }
        __syncthreads();
#pragma unroll 2
        for (int k4 = 0; k4 < 8; ++k4) {
            float a[4][4];
#pragma unroll
            for (int i = 0; i < 4; ++i) {
                float4 v = *(const float4*)&Xs[ty * 4 + i][k4 << 2];
                a[i][0] = v.x; a[i][1] = v.y; a[i][2] = v.z; a[i][3] = v.w;
            }
#pragma unroll
            for (int kk = 0; kk < 4; ++kk) {
                float bb[6];
#pragma unroll
                for (int j = 0; j < 6; ++j) bb[j] = Ws[(k4 << 2) + kk][tx * 6 + j];
#pragma unroll
                for (int i = 0; i < 4; ++i)
#pragma unroll
                    for (int j = 0; j < 6; ++j)
                        acc[i][j] = fmaf(a[i][kk], bb[j], acc[i][j]);
            }
        }
        __syncthreads();
    }
#pragma unroll
    for (int i = 0; i < 4; ++i) {
        int row = m0 + ty * 4 + i;
#pragma unroll
        for (int j = 0; j < 6; ++j) {
            int col = tx * 6 + j;
            float* dst = (col < 64) ? Q : (col < 128) ? K : V;
            dst[(size_t)row * HSD + (col & 63)] = acc[i][j];
        }
    }
}

// ---------------- Kernel 2: causal flash attention ----------------
// One block handles q-tiles {bp, 63-bp} of one batch -> uniform 33 key-tiles.
// Thread grid 16x16: S/O rows ty*2+{0,1}, cols tx*4+{0..3}.
__global__ __launch_bounds__(256) void attn_kernel(
    const float* __restrict__ Q, const float* __restrict__ K,
    const float* __restrict__ V, float* __restrict__ O)
{
    __shared__ float Qs[BQ][HSD + 4];
    __shared__ float Ks[BK * HSD];        // xor-swizzled float4 chunks
    __shared__ float Vs[BK][HSD + 4];
    __shared__ float Ps[BQ][BK + 4];

    const int b  = blockIdx.x >> 5;       // 0..7
    const int bp = blockIdx.x & 31;       // 0..31
    const int t  = threadIdx.x;
    const int ty = t >> 4;                // 0..15
    const int tx = t & 15;                // 0..15

    const float* Kg = K + (size_t)b * SEQ * HSD;
    const float* Vg = V + (size_t)b * SEQ * HSD;

    for (int half = 0; half < 2; ++half) {
        const int qi = half ? (63 - bp) : bp;   // q-tile 0..63
        const int q0 = qi * BQ;
        const float* Qg = Q + ((size_t)b * SEQ + q0) * HSD;

        // load Q tile (all prior Qs readers passed last __syncthreads)
#pragma unroll
        for (int u = 0; u < 2; ++u) {
            int idx = t + u * 256;
            int row = idx >> 4, c4 = (idx & 15) << 2;
            *(float4*)&Qs[row][c4] = *(const float4*)&Qg[(size_t)row * HSD + c4];
        }

        float o[2][4], m[2], l[2];
#pragma unroll
        for (int i = 0; i < 2; ++i) {
            m[i] = -INFINITY; l[i] = 0.f;
#pragma unroll
            for (int h = 0; h < 4; ++h) o[i][h] = 0.f;
        }

        const int jmax = qi >> 1;
        for (int j = 0; j <= jmax; ++j) {
            const int k0 = j * BK;
            __syncthreads();                     // prev PV / S-GEMM done
#pragma unroll
            for (int u = 0; u < 4; ++u) {
                int idx = t + u * 256;           // 0..1023 float4s
                int row = idx >> 4, c4 = idx & 15;
                float4 kv = *(const float4*)&Kg[(size_t)(k0 + row) * HSD + (c4 << 2)];
                float4 vv = *(const float4*)&Vg[(size_t)(k0 + row) * HSD + (c4 << 2)];
                ((float4*)Ks)[row * 16 + ((c4 ^ (row >> 2)) & 15)] = kv;  // swizzle
                *(float4*)&Vs[row][c4 << 2] = vv;
            }
            __syncthreads();

            // ---- S = Q K^T ----
            float s[2][4];
#pragma unroll
            for (int i = 0; i < 2; ++i)
#pragma unroll
                for (int jj = 0; jj < 4; ++jj) s[i][jj] = 0.f;
#pragma unroll 4
            for (int k4 = 0; k4 < 16; ++k4) {
                float qa[2][4], ka[4][4];
#pragma unroll
                for (int i = 0; i < 2; ++i) {
                    float4 v = *(const float4*)&Qs[ty * 2 + i][k4 << 2];
                    qa[i][0] = v.x; qa[i][1] = v.y; qa[i][2] = v.z; qa[i][3] = v.w;
                }
                const int chunk = (k4 ^ tx) & 15;
#pragma unroll
                for (int jj = 0; jj < 4; ++jj) {
                    float4 v = ((const float4*)Ks)[(tx * 4 + jj) * 16 + chunk];
                    ka[jj][0] = v.x; ka[jj][1] = v.y; ka[jj][2] = v.z; ka[jj][3] = v.w;
                }
#pragma unroll
                for (int kk = 0; kk < 4; ++kk)
#pragma unroll
                    for (int i = 0; i < 2; ++i)
#pragma unroll
                        for (int jj = 0; jj < 4; ++jj)
                            s[i][jj] = fmaf(qa[i][kk], ka[jj][kk], s[i][jj]);
            }

            // ---- scale, causal mask, online softmax ----
#pragma unroll
            for (int i = 0; i < 2; ++i) {
                const int row = q0 + ty * 2 + i;
#pragma unroll
                for (int jj = 0; jj < 4; ++jj) {
                    const int col = k0 + tx * 4 + jj;
                    s[i][jj] = (col <= row) ? s[i][jj] * 8.0f : -INFINITY;
                }
                float mt = fmaxf(fmaxf(s[i][0], s[i][1]), fmaxf(s[i][2], s[i][3]));
#pragma unroll
                for (int off = 8; off > 0; off >>= 1)
                    mt = fmaxf(mt, __shfl_xor(mt, off));
                const float mn = fmaxf(m[i], mt);
                const float al = __expf(m[i] - mn);   // exp(-inf)=0 on first tile
                m[i] = mn;
                float4 pv;
                pv.x = __expf(s[i][0] - mn); pv.y = __expf(s[i][1] - mn);
                pv.z = __expf(s[i][2] - mn); pv.w = __expf(s[i][3] - mn);
                float r = pv.x + pv.y + pv.z + pv.w;
#pragma unroll
                for (int off = 8; off > 0; off >>= 1)
                    r += __shfl_xor(r, off);
                l[i] = l[i] * al + r;
                *(float4*)&Ps[ty * 2 + i][tx << 2] = pv;
#pragma unroll
                for (int h = 0; h < 4; ++h) o[i][h] *= al;
            }
            __syncthreads();

            // ---- O += P V ----
#pragma unroll 4
            for (int c4 = 0; c4 < 16; ++c4) {
                float pa[2][4];
#pragma unroll
                for (int i = 0; i < 2; ++i) {
                    float4 v = *(const float4*)&Ps[ty * 2 + i][c4 << 2];
                    pa[i][0] = v.x; pa[i][1] = v.y; pa[i][2] = v.z; pa[i][3] = v.w;
                }
#pragma unroll
                for (int cc = 0; cc < 4; ++cc) {
                    float4 vv = *(const float4*)&Vs[(c4 << 2) + cc][tx << 2];
#pragma unroll
                    for (int i = 0; i < 2; ++i) {
                        o[i][0] = fmaf(pa[i][cc], vv.x, o[i][0]);
                        o[i][1] = fmaf(pa[i][cc], vv.y, o[i][1]);
                        o[i][2] = fmaf(pa[i][cc], vv.z, o[i][2]);
                        o[i][3] = fmaf(pa[i][cc], vv.w, o[i][3]);
                    }
                }
            }
        }

        // ---- epilogue ----
#pragma unroll
        for (int i = 0; i < 2; ++i) {
            const float inv = 1.0f / l[i];
            float4 ov;
            ov.x = o[i][0] * inv; ov.y = o[i][1] * inv;
            ov.z = o[i][2] * inv; ov.w = o[i][3] * inv;
            *(float4*)&O[((size_t)b * SEQ + q0 + ty * 2 + i) * HSD + (tx << 2)] = ov;
        }
    }
}

extern "C" void kernel_launch(void* const* d_in, const int* in_sizes, int n_in,
                              void* d_out, int out_size, void* d_ws, size_t ws_size,
                              hipStream_t stream) {
    const float* X  = (const float*)d_in[0];
    const float* Wq = (const float*)d_in[1];
    const float* Wk = (const float*)d_in[2];
    const float* Wv = (const float*)d_in[3];
    float* Qp = (float*)d_ws;                       // 3 x 16384 x 64 fp32 = 12 MiB
    float* Kp = Qp + (size_t)NROWS * HSD;
    float* Vp = Kp + (size_t)NROWS * HSD;
    float* Og = (float*)d_out;

    qkv_proj_kernel<<<NROWS / 32, 256, 0, stream>>>(X, Wq, Wk, Wv, Qp, Kp, Vp);
    attn_kernel<<<BATCH * 32, 256, 0, stream>>>(Qp, Kp, Vp, Og);
}

// Round 2
// 191.533 us; speedup vs baseline: 1.8946x; 1.8946x over previous
//
#include <hip/hip_runtime.h>
#include <math.h>

typedef float f32x4 __attribute__((ext_vector_type(4)));
typedef __bf16 bf16x8 __attribute__((ext_vector_type(8)));
typedef unsigned short us8 __attribute__((ext_vector_type(8)));
typedef unsigned short us4 __attribute__((ext_vector_type(4)));

__device__ __forceinline__ unsigned short f2bf(float x) {
    unsigned u = __builtin_bit_cast(unsigned, x);
    u += 0x7fffu + ((u >> 16) & 1u);
    return (unsigned short)(u >> 16);
}
__device__ __forceinline__ float bf2f(unsigned short h) {
    unsigned u = ((unsigned)h) << 16;
    return __builtin_bit_cast(float, u);
}
__device__ __forceinline__ f32x4 mfma16(us8 a, us8 b, f32x4 c) {
    return __builtin_amdgcn_mfma_f32_16x16x32_bf16(
        __builtin_bit_cast(bf16x8, a), __builtin_bit_cast(bf16x8, b), c, 0, 0, 0);
}

// ---------------- Kernel 0: W transpose + split ----------------
// W_g (1024x64 fp32) -> Wt_hi/Wt_lo[g*64+h][k] bf16 (192x1024 each)
__global__ __launch_bounds__(256) void wprep_kernel(
    const float* __restrict__ Wq, const float* __restrict__ Wk,
    const float* __restrict__ Wv,
    unsigned short* __restrict__ Wthi, unsigned short* __restrict__ Wtlo)
{
    __shared__ __align__(16) float Ls[64][68];
    const int g = blockIdx.x >> 4;
    const int k0 = (blockIdx.x & 15) << 6;
    const float* W = (g == 0) ? Wq : (g == 1) ? Wk : Wv;
    const int t = threadIdx.x;
#pragma unroll
    for (int u = 0; u < 4; ++u) {
        int idx = t + (u << 8);
        int row = idx >> 4, c4 = (idx & 15) << 2;
        *(float4*)&Ls[row][c4] = *(const float4*)&W[(size_t)(k0 + row) * 64 + c4];
    }
    __syncthreads();
    const int h = t >> 2, kk0 = (t & 3) << 4;
    size_t base = (size_t)((g << 6) + h) * 1024 + k0 + kk0;
#pragma unroll
    for (int c = 0; c < 4; ++c) {
        us4 hv, lv;
#pragma unroll
        for (int i = 0; i < 4; ++i) {
            float x = Ls[kk0 + (c << 2) + i][h];
            unsigned short hh = f2bf(x);
            hv[i] = hh;
            lv[i] = f2bf(x - bf2f(hh));
        }
        *(us4*)&Wthi[base + (c << 2)] = hv;
        *(us4*)&Wtlo[base + (c << 2)] = lv;
    }
}

// ---------------- Kernel 1: fused QKV projection (split-bf16 MFMA) -------
// X(16384x1024 fp32) @ W(1024x192) -> Qhi/Qlo/Khi/Klo row-major (16384x64),
// V transposed: Vthi[b*64+h][t] bf16. Block tile 128x96, 4 waves (64x48 ea).
__global__ __launch_bounds__(256) void qkv_kernel(
    const float* __restrict__ X,
    const unsigned short* __restrict__ Wthi,
    const unsigned short* __restrict__ Wtlo,
    unsigned short* __restrict__ Qhi, unsigned short* __restrict__ Qlo,
    unsigned short* __restrict__ Khi, unsigned short* __restrict__ Klo,
    unsigned short* __restrict__ Vthi)
{
    __shared__ __align__(16) unsigned short Xh[128][40], Xl[128][40];
    __shared__ __align__(16) unsigned short Wh[96][40], Wl[96][40];
    __shared__ __align__(16) unsigned short Vx[4][16][20];

    const int t = threadIdx.x;
    const int w = t >> 6, l = t & 63, lm = l & 15, lg = l >> 4;
    const int wrow = (w >> 1) << 6;       // 0 / 64
    const int wcol = (w & 1) * 48;        // 0 / 48
    const int m0 = blockIdx.x << 7;
    const int y = blockIdx.y;

    const int xrow = t >> 1, xhalf = (t & 1) << 4;

    f32x4 acc[4][3];
#pragma unroll
    for (int i = 0; i < 4; ++i)
#pragma unroll
        for (int j = 0; j < 3; ++j) acc[i][j] = (f32x4){0.f, 0.f, 0.f, 0.f};

    for (int k0 = 0; k0 < 1024; k0 += 32) {
        // global loads first (overlap with prior compute)
        float4 xv[4];
        const float* xp = &X[(size_t)(m0 + xrow) * 1024 + k0 + xhalf];
#pragma unroll
        for (int i = 0; i < 4; ++i) xv[i] = *(const float4*)&xp[i << 2];
        us4 wvh[3], wvl[3];
#pragma unroll
        for (int u = 0; u < 3; ++u) {
            int idx = t + (u << 8);
            int n = idx >> 3, c = idx & 7;
            size_t off = (size_t)(y * 96 + n) * 1024 + k0 + (c << 2);
            wvh[u] = *(const us4*)&Wthi[off];
            wvl[u] = *(const us4*)&Wtlo[off];
        }
        __syncthreads();          // prior frag readers done
        {
            float xf[16];
#pragma unroll
            for (int i = 0; i < 4; ++i) {
                xf[4*i] = xv[i].x; xf[4*i+1] = xv[i].y;
                xf[4*i+2] = xv[i].z; xf[4*i+3] = xv[i].w;
            }
            us8 h0, h1, l0v, l1v;
#pragma unroll
            for (int e = 0; e < 8; ++e) {
                unsigned short a = f2bf(xf[e]);
                h0[e] = a; l0v[e] = f2bf(xf[e] - bf2f(a));
                unsigned short bqq = f2bf(xf[e + 8]);
                h1[e] = bqq; l1v[e] = f2bf(xf[e + 8] - bf2f(bqq));
            }
            *(us8*)&Xh[xrow][xhalf]     = h0;
            *(us8*)&Xh[xrow][xhalf + 8] = h1;
            *(us8*)&Xl[xrow][xhalf]     = l0v;
            *(us8*)&Xl[xrow][xhalf + 8] = l1v;
#pragma unroll
            for (int u = 0; u < 3; ++u) {
                int idx = t + (u << 8);
                int n = idx >> 3, c = idx & 7;
                *(us4*)&Wh[n][c << 2] = wvh[u];
                *(us4*)&Wl[n][c << 2] = wvl[u];
            }
        }
        __syncthreads();
        us8 ah[4], al[4], bh[3], bl[3];
#pragma unroll
        for (int rt = 0; rt < 4; ++rt) {
            int r = wrow + (rt << 4) + lm;
            ah[rt] = *(const us8*)&Xh[r][lg << 3];
            al[rt] = *(const us8*)&Xl[r][lg << 3];
        }
#pragma unroll
        for (int ct = 0; ct < 3; ++ct) {
            int n = wcol + (ct << 4) + lm;
            bh[ct] = *(const us8*)&Wh[n][lg << 3];
            bl[ct] = *(const us8*)&Wl[n][lg << 3];
        }
#pragma unroll
        for (int rt = 0; rt < 4; ++rt)
#pragma unroll
            for (int ct = 0; ct < 3; ++ct) {
                acc[rt][ct] = mfma16(ah[rt], bh[ct], acc[rt][ct]);
                acc[rt][ct] = mfma16(ah[rt], bl[ct], acc[rt][ct]);
                acc[rt][ct] = mfma16(al[rt], bh[ct], acc[rt][ct]);
            }
    }

    // epilogue: C layout col=lane&15, row=(lane>>4)*4+reg
    const int tb_row = m0 + wrow;
#pragma unroll
    for (int rt = 0; rt < 4; ++rt) {
#pragma unroll
        for (int ct = 0; ct < 3; ++ct) {
            const int gc = y * 96 + wcol + (ct << 4);   // tile col base (0..176)
            const int arr = gc >> 6;
            if (arr < 2) {
                unsigned short* Dh = arr ? Khi : Qhi;
                unsigned short* Dl = arr ? Klo : Qlo;
                const int colb = (gc & 63) + lm;
#pragma unroll
                for (int r = 0; r < 4; ++r) {
                    int row = tb_row + (rt << 4) + (lg << 2) + r;
                    float x = acc[rt][ct][r];
                    unsigned short hh = f2bf(x);
                    size_t o = (size_t)row * 64 + colb;
                    Dh[o] = hh;
                    Dl[o] = f2bf(x - bf2f(hh));
                }
            } else {
                // V: transpose 16x16 via LDS (wave-synchronous, in-order DS)
#pragma unroll
                for (int r = 0; r < 4; ++r)
                    Vx[w][lm][(lg << 2) + r] = f2bf(acc[rt][ct][r]);
                __asm__ volatile("" ::: "memory");
                const int h0 = gc - 128;
                const int tb = tb_row + (rt << 4);
                const int b = tb >> 11;
                const int tl = (tb & 2047) + ((l & 3) << 2);
                const int hh2 = h0 + (l >> 2);
                us4 vv = *(const us4*)&Vx[w][l >> 2][(l & 3) << 2];
                *(us4*)&Vthi[(size_t)((b << 6) + hh2) * 2048 + tl] = vv;
                __asm__ volatile("" ::: "memory");
            }
        }
    }
}

// ---------------- Kernel 2: causal flash attention (MFMA) ----------------
// Block = (b, qi) with qi descending; 4 waves = 2 q-rowtiles x 2 key-parities.
// Each wave: 16 q-rows, online softmax over its key-tiles; merge at end.
__global__ __launch_bounds__(256) void attn_kernel(
    const unsigned short* __restrict__ Qhi, const unsigned short* __restrict__ Qlo,
    const unsigned short* __restrict__ Khi, const unsigned short* __restrict__ Klo,
    const unsigned short* __restrict__ Vthi,
    float* __restrict__ O)
{
    __shared__ __align__(16) unsigned short Kh[2][64][72];
    __shared__ __align__(16) unsigned short Kl[2][64][72];
    __shared__ __align__(16) unsigned short Vh[2][64][72];
    __shared__ __align__(16) unsigned short Ps[4][16][72];

    const int t = threadIdx.x;
    const int w = t >> 6, l = t & 63, lm = l & 15, lg = l >> 4;
    const int rt = w >> 1, ks = w & 1;
    const int b = blockIdx.x & 7;
    const int qi = 63 - (blockIdx.x >> 3);     // long blocks first
    const int nk = (qi >> 1) + 1;              // 64-key tiles needed
    const int iters = (nk + 1) >> 1;
    const int q0 = (qi << 5) + (rt << 4);
    const size_t qrow = ((size_t)b << 11) + q0;

    // Q fragments pinned in registers (A-layout: m=lane&15, k=quad*8+j)
    us8 qh[2], ql[2];
#pragma unroll
    for (int kc = 0; kc < 2; ++kc) {
        size_t off = (qrow + lm) * 64 + (kc << 5) + (lg << 3);
        qh[kc] = *(const us8*)&Qhi[off];
        ql[kc] = *(const us8*)&Qlo[off];
    }

    f32x4 o_acc[4];
#pragma unroll
    for (int ct = 0; ct < 4; ++ct) o_acc[ct] = (f32x4){0.f, 0.f, 0.f, 0.f};
    float m_r[4], l_r[4];
#pragma unroll
    for (int r = 0; r < 4; ++r) { m_r[r] = -INFINITY; l_r[r] = 0.f; }

    // staging role within pair (region = this wave's ks)
    const int srow = (rt << 6) | l;            // 0..127
    const int krow = srow >> 1, khalf = (srow & 1) << 5;

    for (int it = 0; it < iters; ++it) {
        const int j = (it << 1) + ks;
        const bool act = j < nk;
        const int kk0 = j << 6;
        us8 stk[4], stl[4], stv[4];
        if (act) {
            const unsigned short* kp = &Khi[(((size_t)b << 11) + kk0 + krow) * 64 + khalf];
            const unsigned short* lp = &Klo[(((size_t)b << 11) + kk0 + krow) * 64 + khalf];
            const unsigned short* vp = &Vthi[(((size_t)b << 6) + krow) * 2048 + kk0 + khalf];
#pragma unroll
            for (int i = 0; i < 4; ++i) {
                stk[i] = *(const us8*)&kp[i << 3];
                stl[i] = *(const us8*)&lp[i << 3];
                stv[i] = *(const us8*)&vp[i << 3];
            }
        }
        __syncthreads();
        if (act) {
#pragma unroll
            for (int i = 0; i < 4; ++i) {
                *(us8*)&Kh[ks][krow][khalf + (i << 3)] = stk[i];
                *(us8*)&Kl[ks][krow][khalf + (i << 3)] = stl[i];
                *(us8*)&Vh[ks][krow][khalf + (i << 3)] = stv[i];
            }
        }
        __syncthreads();
        if (!act) continue;

        // ---- S = Q K^T (split-bf16: 3 MFMA per tile-chunk) ----
        f32x4 s[4];
#pragma unroll
        for (int ct = 0; ct < 4; ++ct) s[ct] = (f32x4){0.f, 0.f, 0.f, 0.f};
#pragma unroll
        for (int ct = 0; ct < 4; ++ct)
#pragma unroll
            for (int kc = 0; kc < 2; ++kc) {
                us8 kbh = *(const us8*)&Kh[ks][(ct << 4) + lm][(kc << 5) + (lg << 3)];
                us8 kbl = *(const us8*)&Kl[ks][(ct << 4) + lm][(kc << 5) + (lg << 3)];
                s[ct] = mfma16(qh[kc], kbh, s[ct]);
                s[ct] = mfma16(qh[kc], kbl, s[ct]);
                s[ct] = mfma16(ql[kc], kbh, s[ct]);
            }

        // ---- scale x8, causal mask, online softmax (per 4 owned rows) ----
#pragma unroll
        for (int r = 0; r < 4; ++r) {
            const int qr = q0 + (lg << 2) + r;
            float sv[4], mx = -INFINITY;
#pragma unroll
            for (int ct = 0; ct < 4; ++ct) {
                int key = kk0 + (ct << 4) + lm;
                sv[ct] = (key <= qr) ? s[ct][r] * 8.0f : -INFINITY;
                mx = fmaxf(mx, sv[ct]);
            }
            mx = fmaxf(mx, __shfl_xor(mx, 1));
            mx = fmaxf(mx, __shfl_xor(mx, 2));
            mx = fmaxf(mx, __shfl_xor(mx, 4));
            mx = fmaxf(mx, __shfl_xor(mx, 8));
            float mn = fmaxf(m_r[r], mx);
            float al = __expf(m_r[r] - mn);    // exp(-inf)=0 first tile
            m_r[r] = mn;
            float rs = 0.f;
#pragma unroll
            for (int ct = 0; ct < 4; ++ct) {
                float pv = __expf(sv[ct] - mn);
                rs += pv;
                Ps[w][(lg << 2) + r][(ct << 4) + lm] = f2bf(pv);
            }
            rs += __shfl_xor(rs, 1);
            rs += __shfl_xor(rs, 2);
            rs += __shfl_xor(rs, 4);
            rs += __shfl_xor(rs, 8);
            l_r[r] = l_r[r] * al + rs;
#pragma unroll
            for (int ct = 0; ct < 4; ++ct) o_acc[ct][r] *= al;
        }
        __asm__ volatile("" ::: "memory");   // P write -> read (same wave, in-order DS)

        // ---- O += P V ----
#pragma unroll
        for (int kc = 0; kc < 2; ++kc) {
            us8 pa = *(const us8*)&Ps[w][lm][(kc << 5) + (lg << 3)];
#pragma unroll
            for (int ct = 0; ct < 4; ++ct) {
                us8 vb = *(const us8*)&Vh[ks][(ct << 4) + lm][(kc << 5) + (lg << 3)];
                o_acc[ct] = mfma16(pa, vb, o_acc[ct]);
            }
        }
    }

    // ---- merge key-parity halves, normalize, store ----
    __syncthreads();
    float* Lo = (float*)&Ps[0][0][0];
    float* Lm = Lo + 2048;
    if (ks == 1) {
#pragma unroll
        for (int ct = 0; ct < 4; ++ct)
#pragma unroll
            for (int r = 0; r < 4; ++r)
                Lo[(rt << 10) + (((lg << 2) + r) << 6) + (ct << 4) + lm] = o_acc[ct][r];
        if (lm == 0) {
#pragma unroll
            for (int r = 0; r < 4; ++r) {
                Lm[(rt << 5) + (lg << 2) + r] = m_r[r];
                Lm[(rt << 5) + 16 + (lg << 2) + r] = l_r[r];
            }
        }
    }
    __syncthreads();
    if (ks == 0) {
#pragma unroll
        for (int r = 0; r < 4; ++r) {
            const int row = (lg << 2) + r;
            float m1 = Lm[(rt << 5) + row];
            float l1 = Lm[(rt << 5) + 16 + row];
            float ms = fmaxf(m_r[r], m1);       // m_r finite (tile 0 always valid)
            float a0 = __expf(m_r[r] - ms);
            float a1 = __expf(m1 - ms);         // 0 if other half empty
            float li = 1.0f / (l_r[r] * a0 + l1 * a1);
#pragma unroll
            for (int ct = 0; ct < 4; ++ct) {
                float o1 = Lo[(rt << 10) + (row << 6) + (ct << 4) + lm];
                O[(qrow + row) * 64 + (ct << 4) + lm] = (o_acc[ct][r] * a0 + o1 * a1) * li;
            }
        }
    }
}

extern "C" void kernel_launch(void* const* d_in, const int* in_sizes, int n_in,
                              void* d_out, int out_size, void* d_ws, size_t ws_size,
                              hipStream_t stream) {
    const float* X  = (const float*)d_in[0];
    const float* Wq = (const float*)d_in[1];
    const float* Wk = (const float*)d_in[2];
    const float* Wv = (const float*)d_in[3];
    unsigned short* ws = (unsigned short*)d_ws;
    const size_t SZ = (size_t)16384 * 64;
    unsigned short* Qhi  = ws;
    unsigned short* Qlo  = ws + SZ;
    unsigned short* Khi  = ws + 2 * SZ;
    unsigned short* Klo  = ws + 3 * SZ;
    unsigned short* Vthi = ws + 4 * SZ;
    unsigned short* Wthi = ws + 5 * SZ;
    unsigned short* Wtlo = Wthi + 192 * 1024;

    wprep_kernel<<<48, 256, 0, stream>>>(Wq, Wk, Wv, Wthi, Wtlo);
    qkv_kernel<<<dim3(128, 2), 256, 0, stream>>>(X, Wthi, Wtlo,
                                                 Qhi, Qlo, Khi, Klo, Vthi);
    attn_kernel<<<512, 256, 0, stream>>>(Qhi, Qlo, Khi, Klo, Vthi, (float*)d_out);
}

// Round 3
// 181.382 us; speedup vs baseline: 2.0006x; 1.0560x over previous
//
#include <hip/hip_runtime.h>
#include <math.h>

typedef float f32x4 __attribute__((ext_vector_type(4)));
typedef __bf16 bf16x8 __attribute__((ext_vector_type(8)));
typedef unsigned short us8 __attribute__((ext_vector_type(8)));
typedef unsigned short us4 __attribute__((ext_vector_type(4)));

__device__ __forceinline__ unsigned short f2bf(float x) {
    unsigned u = __builtin_bit_cast(unsigned, x);
    u += 0x7fffu + ((u >> 16) & 1u);
    return (unsigned short)(u >> 16);
}
__device__ __forceinline__ float bf2f(unsigned short h) {
    unsigned u = ((unsigned)h) << 16;
    return __builtin_bit_cast(float, u);
}
__device__ __forceinline__ f32x4 mfma16(us8 a, us8 b, f32x4 c) {
    return __builtin_amdgcn_mfma_f32_16x16x32_bf16(
        __builtin_bit_cast(bf16x8, a), __builtin_bit_cast(bf16x8, b), c, 0, 0, 0);
}
// async global->LDS, 16B/lane; LDS dest = wave-uniform base + lane*16
__device__ __forceinline__ void glds16(const unsigned short* g, unsigned short* l) {
    __builtin_amdgcn_global_load_lds(
        (const __attribute__((address_space(1))) unsigned int*)g,
        (__attribute__((address_space(3))) unsigned int*)l, 16, 0, 0);
}

// ---------------- Kernel 0: W transpose + split ----------------
__global__ __launch_bounds__(256) void wprep_kernel(
    const float* __restrict__ Wq, const float* __restrict__ Wk,
    const float* __restrict__ Wv,
    unsigned short* __restrict__ Wthi, unsigned short* __restrict__ Wtlo)
{
    __shared__ __align__(16) float Ls[64][68];
    const int g = blockIdx.x >> 4;
    const int k0 = (blockIdx.x & 15) << 6;
    const float* W = (g == 0) ? Wq : (g == 1) ? Wk : Wv;
    const int t = threadIdx.x;
#pragma unroll
    for (int u = 0; u < 4; ++u) {
        int idx = t + (u << 8);
        int row = idx >> 4, c4 = (idx & 15) << 2;
        *(float4*)&Ls[row][c4] = *(const float4*)&W[(size_t)(k0 + row) * 64 + c4];
    }
    __syncthreads();
    const int h = t >> 2, kk0 = (t & 3) << 4;
    size_t base = (size_t)((g << 6) + h) * 1024 + k0 + kk0;
#pragma unroll
    for (int c = 0; c < 4; ++c) {
        us4 hv, lv;
#pragma unroll
        for (int i = 0; i < 4; ++i) {
            float x = Ls[kk0 + (c << 2) + i][h];
            unsigned short hh = f2bf(x);
            hv[i] = hh;
            lv[i] = f2bf(x - bf2f(hh));
        }
        *(us4*)&Wthi[base + (c << 2)] = hv;
        *(us4*)&Wtlo[base + (c << 2)] = lv;
    }
}

// ---------------- Kernel 1: fused QKV projection ----------------
// Tile 64x96, grid (256,2) = 2 blocks/CU. A-frags direct from global
// (trunc-hi split), W via double-buffered swizzled global_load_lds.
// Q outputs pre-scaled by 8 (folds softmax scale into projection).
__global__ __launch_bounds__(256) void qkv_kernel(
    const float* __restrict__ X,
    const unsigned short* __restrict__ Wthi,
    const unsigned short* __restrict__ Wtlo,
    unsigned short* __restrict__ Qhi, unsigned short* __restrict__ Qlo,
    unsigned short* __restrict__ Khi, unsigned short* __restrict__ Klo,
    unsigned short* __restrict__ Vthi)
{
    __shared__ __align__(16) unsigned short Wb[2][2][96 * 32]; // [buf][hi/lo], swizzled
    __shared__ __align__(16) unsigned short Vx[4][16][20];

    const int t = threadIdx.x;
    const int w = t >> 6, l = t & 63, lm = l & 15, lg = l >> 4;
    const int wq = w >> 1, wc = w & 1;
    const int m0 = blockIdx.x << 6;
    const int y  = blockIdx.y;

    // staging descriptors: 12 glds/iter, 3 per wave; 16 W-rows (64B) per glds
    const unsigned short* gsb[3];
    unsigned short* lsb[3][2];
#pragma unroll
    for (int i = 0; i < 3; ++i) {
        int u = w * 3 + i;
        int p = (u >= 6) ? 1 : 0;
        int rb = (u % 6) << 4;
        int n = rb + (l >> 2);
        int cg = (l & 3) ^ ((n >> 1) & 3);      // slot (l&3) holds global chunk cg
        gsb[i] = (p ? Wtlo : Wthi) + (size_t)(y * 96 + n) * 1024 + (cg << 3);
        lsb[i][0] = &Wb[0][p][rb << 5];
        lsb[i][1] = &Wb[1][p][rb << 5];
    }
    const float* xp0 = X + (size_t)(m0 + (wq << 5) + lm) * 1024 + (lg << 3);

    f32x4 acc[2][3];
#pragma unroll
    for (int i = 0; i < 2; ++i)
#pragma unroll
        for (int j = 0; j < 3; ++j) acc[i][j] = (f32x4){0.f, 0.f, 0.f, 0.f};

    // prologue
#pragma unroll
    for (int i = 0; i < 3; ++i) glds16(gsb[i], lsb[i][0]);
    float4 xn[4];
#pragma unroll
    for (int rt = 0; rt < 2; ++rt)
#pragma unroll
        for (int c = 0; c < 2; ++c)
            xn[rt * 2 + c] = *(const float4*)(xp0 + rt * 16384 + (c << 2));

    for (int k = 0; k < 32; ++k) {
        const int kb = k & 1;
        // convert current X regs -> A frags (trunc-hi split: 6 VALU/elem)
        us8 ah[2], al[2];
#pragma unroll
        for (int rt = 0; rt < 2; ++rt) {
            float xf[8];
            xf[0] = xn[rt*2].x; xf[1] = xn[rt*2].y; xf[2] = xn[rt*2].z; xf[3] = xn[rt*2].w;
            xf[4] = xn[rt*2+1].x; xf[5] = xn[rt*2+1].y; xf[6] = xn[rt*2+1].z; xf[7] = xn[rt*2+1].w;
            us8 h, lo;
#pragma unroll
            for (int e = 0; e < 8; ++e) {
                unsigned u = __builtin_bit_cast(unsigned, xf[e]);
                h[e] = (unsigned short)(u >> 16);
                float hf = __builtin_bit_cast(float, u & 0xffff0000u);
                lo[e] = f2bf(xf[e] - hf);
            }
            ah[rt] = h; al[rt] = lo;
        }
        __syncthreads();                          // buf[kb] DMA drained; prev reads done
        if (k < 31) {
            const int k0n = (k + 1) << 5;
#pragma unroll
            for (int i = 0; i < 3; ++i) glds16(gsb[i] + k0n, lsb[i][kb ^ 1]);
#pragma unroll
            for (int rt = 0; rt < 2; ++rt)
#pragma unroll
                for (int c = 0; c < 2; ++c)
                    xn[rt * 2 + c] = *(const float4*)(xp0 + rt * 16384 + k0n + (c << 2));
        }
        us8 bh[3], bl[3];
#pragma unroll
        for (int ct = 0; ct < 3; ++ct) {
            int n = wc * 48 + (ct << 4) + lm;
            int slot = lg ^ ((n >> 1) & 3);
            bh[ct] = *(const us8*)&Wb[kb][0][(n << 5) + (slot << 3)];
            bl[ct] = *(const us8*)&Wb[kb][1][(n << 5) + (slot << 3)];
        }
#pragma unroll
        for (int rt = 0; rt < 2; ++rt)
#pragma unroll
            for (int ct = 0; ct < 3; ++ct) {
                acc[rt][ct] = mfma16(ah[rt], bh[ct], acc[rt][ct]);
                acc[rt][ct] = mfma16(ah[rt], bl[ct], acc[rt][ct]);
                acc[rt][ct] = mfma16(al[rt], bh[ct], acc[rt][ct]);
            }
    }

    // epilogue: C layout col=lane&15, row=(lane>>4)*4+reg
    const int tbr = m0 + (wq << 5);
#pragma unroll
    for (int rt = 0; rt < 2; ++rt) {
#pragma unroll
        for (int ct = 0; ct < 3; ++ct) {
            const int gc = y * 96 + wc * 48 + (ct << 4);
            if (gc < 128) {
                unsigned short* Dh = (gc < 64) ? Qhi : Khi;
                unsigned short* Dl = (gc < 64) ? Qlo : Klo;
                const float sc = (gc < 64) ? 8.0f : 1.0f;   // fold sqrt(hs) into Q
                const int colb = (gc & 63) + lm;
#pragma unroll
                for (int r = 0; r < 4; ++r) {
                    int row = tbr + (rt << 4) + (lg << 2) + r;
                    float x = acc[rt][ct][r] * sc;
                    unsigned short hh = f2bf(x);
                    size_t o = (size_t)row * 64 + colb;
                    Dh[o] = hh;
                    Dl[o] = f2bf(x - bf2f(hh));
                }
            } else {
                // V: transpose 16x16 via wave-local LDS
#pragma unroll
                for (int r = 0; r < 4; ++r)
                    Vx[w][lm][(lg << 2) + r] = f2bf(acc[rt][ct][r]);
                __asm__ volatile("" ::: "memory");
                const int h0 = gc - 128;
                const int tb = tbr + (rt << 4);
                const int bb = tb >> 11;
                const int tl = (tb & 2047) + ((l & 3) << 2);
                const int hh2 = h0 + (l >> 2);
                us4 vv = *(const us4*)&Vx[w][l >> 2][(l & 3) << 2];
                *(us4*)&Vthi[(size_t)((bb << 6) + hh2) * 2048 + tl] = vv;
                __asm__ volatile("" ::: "memory");
            }
        }
    }
}

// ---------------- Kernel 2: causal flash attention (MFMA) ----------------
// 512 blocks = (b, qi desc); 4 waves = 2 q-rowtiles x 2 key-parities.
// Register-prefetch of tile j+2 overlaps global latency with compute.
__global__ __launch_bounds__(256) void attn_kernel(
    const unsigned short* __restrict__ Qhi, const unsigned short* __restrict__ Qlo,
    const unsigned short* __restrict__ Khi, const unsigned short* __restrict__ Klo,
    const unsigned short* __restrict__ Vthi,
    float* __restrict__ O)
{
    __shared__ __align__(16) unsigned short Kh[2][64][72];
    __shared__ __align__(16) unsigned short Kl[2][64][72];
    __shared__ __align__(16) unsigned short Vh[2][64][72];
    __shared__ __align__(16) unsigned short Ps[4][16][80];

    const int t = threadIdx.x;
    const int w = t >> 6, l = t & 63, lm = l & 15, lg = l >> 4;
    const int rt = w >> 1, ks = w & 1;
    const int b = blockIdx.x & 7;
    const int qi = 63 - (blockIdx.x >> 3);
    const int nk = (qi >> 1) + 1;
    const int iters = (nk + 1) >> 1;
    const int q0 = (qi << 5) + (rt << 4);
    const size_t qrow = ((size_t)b << 11) + q0;

    us8 qh[2], ql[2];
#pragma unroll
    for (int kc = 0; kc < 2; ++kc) {
        size_t off = (qrow + lm) * 64 + (kc << 5) + (lg << 3);
        qh[kc] = *(const us8*)&Qhi[off];
        ql[kc] = *(const us8*)&Qlo[off];
    }

    f32x4 o_acc[4];
#pragma unroll
    for (int ct = 0; ct < 4; ++ct) o_acc[ct] = (f32x4){0.f, 0.f, 0.f, 0.f};
    float m_r[4], l_r[4];
#pragma unroll
    for (int r = 0; r < 4; ++r) { m_r[r] = -INFINITY; l_r[r] = 0.f; }

    const int srow = (rt << 6) | l;
    const int krow = srow >> 1, khalf = (srow & 1) << 5;
    const unsigned short* kpb = &Khi[(((size_t)b << 11) + krow) * 64 + khalf];
    const unsigned short* lpb = &Klo[(((size_t)b << 11) + krow) * 64 + khalf];
    const unsigned short* vpb = &Vthi[(((size_t)b << 6) + krow) * 2048 + khalf];

    us8 stk[4], stl[4], stv[4];
    {
        const int j0 = (ks < nk) ? ks : 0;
        const int ko = j0 << 12, vo = j0 << 6;
#pragma unroll
        for (int i = 0; i < 4; ++i) {
            stk[i] = *(const us8*)&kpb[ko + (i << 3)];
            stl[i] = *(const us8*)&lpb[ko + (i << 3)];
            stv[i] = *(const us8*)&vpb[vo + (i << 3)];
        }
    }

    for (int it = 0; it < iters; ++it) {
        const int j = (it << 1) + ks;
        const bool act = j < nk;
        const int kk0 = j << 6;
        __syncthreads();                       // prev compute's LDS reads done
        if (act) {
#pragma unroll
            for (int i = 0; i < 4; ++i) {
                *(us8*)&Kh[ks][krow][khalf + (i << 3)] = stk[i];
                *(us8*)&Kl[ks][krow][khalf + (i << 3)] = stl[i];
                *(us8*)&Vh[ks][krow][khalf + (i << 3)] = stv[i];
            }
        }
        const int jn = j + 2;                  // prefetch next tile -> regs
        if (jn < nk) {
            const int ko = jn << 12, vo = jn << 6;
#pragma unroll
            for (int i = 0; i < 4; ++i) {
                stk[i] = *(const us8*)&kpb[ko + (i << 3)];
                stl[i] = *(const us8*)&lpb[ko + (i << 3)];
                stv[i] = *(const us8*)&vpb[vo + (i << 3)];
            }
        }
        __syncthreads();                       // tiles visible
        if (!act) continue;

        // ---- S = Q K^T (split-bf16, 3 MFMA) ----
        f32x4 s[4];
#pragma unroll
        for (int ct = 0; ct < 4; ++ct) s[ct] = (f32x4){0.f, 0.f, 0.f, 0.f};
#pragma unroll
        for (int ct = 0; ct < 4; ++ct)
#pragma unroll
            for (int kc = 0; kc < 2; ++kc) {
                us8 kbh = *(const us8*)&Kh[ks][(ct << 4) + lm][(kc << 5) + (lg << 3)];
                us8 kbl = *(const us8*)&Kl[ks][(ct << 4) + lm][(kc << 5) + (lg << 3)];
                s[ct] = mfma16(qh[kc], kbh, s[ct]);
                s[ct] = mfma16(qh[kc], kbl, s[ct]);
                s[ct] = mfma16(ql[kc], kbh, s[ct]);
            }

        // ---- mask + online softmax (scale pre-folded into Q) ----
        const bool full = (kk0 + 63) <= q0;    // wave-uniform: tile fully visible
#pragma unroll
        for (int r = 0; r < 4; ++r) {
            const int qr = q0 + (lg << 2) + r;
            float sv[4];
            if (full) {
                sv[0] = s[0][r]; sv[1] = s[1][r]; sv[2] = s[2][r]; sv[3] = s[3][r];
            } else {
#pragma unroll
                for (int ct = 0; ct < 4; ++ct) {
                    const int key = kk0 + (ct << 4) + lm;
                    sv[ct] = (key <= qr) ? s[ct][r] : -INFINITY;
                }
            }
            float mx = fmaxf(fmaxf(sv[0], sv[1]), fmaxf(sv[2], sv[3]));
            mx = fmaxf(mx, __shfl_xor(mx, 1));
            mx = fmaxf(mx, __shfl_xor(mx, 2));
            mx = fmaxf(mx, __shfl_xor(mx, 4));
            mx = fmaxf(mx, __shfl_xor(mx, 8));
            const float mn = fmaxf(m_r[r], mx);
            const float alz = __expf(m_r[r] - mn);
            m_r[r] = mn;
            float rs = 0.f;
#pragma unroll
            for (int ct = 0; ct < 4; ++ct) {
                float pv = __expf(sv[ct] - mn);
                rs += pv;
                Ps[w][(lg << 2) + r][(ct << 4) + lm] = f2bf(pv);
            }
            rs += __shfl_xor(rs, 1);
            rs += __shfl_xor(rs, 2);
            rs += __shfl_xor(rs, 4);
            rs += __shfl_xor(rs, 8);
            l_r[r] = l_r[r] * alz + rs;
#pragma unroll
            for (int ct = 0; ct < 4; ++ct) o_acc[ct][r] *= alz;
        }
        __asm__ volatile("" ::: "memory");     // P write->read, same wave in-order DS

        // ---- O += P V ----
#pragma unroll
        for (int kc = 0; kc < 2; ++kc) {
            us8 pa = *(const us8*)&Ps[w][lm][(kc << 5) + (lg << 3)];
#pragma unroll
            for (int ct = 0; ct < 4; ++ct) {
                us8 vb = *(const us8*)&Vh[ks][(ct << 4) + lm][(kc << 5) + (lg << 3)];
                o_acc[ct] = mfma16(pa, vb, o_acc[ct]);
            }
        }
    }

    // ---- merge key-parity halves, normalize, store ----
    __syncthreads();
    float* Lo = (float*)&Ps[0][0][0];
    float* Lm = Lo + 2048;
    if (ks == 1) {
#pragma unroll
        for (int ct = 0; ct < 4; ++ct)
#pragma unroll
            for (int r = 0; r < 4; ++r)
                Lo[(rt << 10) + (((lg << 2) + r) << 6) + (ct << 4) + lm] = o_acc[ct][r];
        if (lm == 0) {
#pragma unroll
            for (int r = 0; r < 4; ++r) {
                Lm[(rt << 5) + (lg << 2) + r] = m_r[r];
                Lm[(rt << 5) + 16 + (lg << 2) + r] = l_r[r];
            }
        }
    }
    __syncthreads();
    if (ks == 0) {
#pragma unroll
        for (int r = 0; r < 4; ++r) {
            const int row = (lg << 2) + r;
            float m1 = Lm[(rt << 5) + row];
            float l1 = Lm[(rt << 5) + 16 + row];
            float ms = fmaxf(m_r[r], m1);
            float a0 = __expf(m_r[r] - ms);
            float a1 = __expf(m1 - ms);
            float li = 1.0f / (l_r[r] * a0 + l1 * a1);
#pragma unroll
            for (int ct = 0; ct < 4; ++ct) {
                float o1 = Lo[(rt << 10) + (row << 6) + (ct << 4) + lm];
                O[(qrow + row) * 64 + (ct << 4) + lm] = (o_acc[ct][r] * a0 + o1 * a1) * li;
            }
        }
    }
}

extern "C" void kernel_launch(void* const* d_in, const int* in_sizes, int n_in,
                              void* d_out, int out_size, void* d_ws, size_t ws_size,
                              hipStream_t stream) {
    const float* X  = (const float*)d_in[0];
    const float* Wq = (const float*)d_in[1];
    const float* Wk = (const float*)d_in[2];
    const float* Wv = (const float*)d_in[3];
    unsigned short* ws = (unsigned short*)d_ws;
    const size_t SZ = (size_t)16384 * 64;
    unsigned short* Qhi  = ws;
    unsigned short* Qlo  = ws + SZ;
    unsigned short* Khi  = ws + 2 * SZ;
    unsigned short* Klo  = ws + 3 * SZ;
    unsigned short* Vthi = ws + 4 * SZ;
    unsigned short* Wthi = ws + 5 * SZ;
    unsigned short* Wtlo = Wthi + 192 * 1024;

    wprep_kernel<<<48, 256, 0, stream>>>(Wq, Wk, Wv, Wthi, Wtlo);
    qkv_kernel<<<dim3(256, 2), 256, 0, stream>>>(X, Wthi, Wtlo,
                                                 Qhi, Qlo, Khi, Klo, Vthi);
    attn_kernel<<<512, 256, 0, stream>>>(Qhi, Qlo, Khi, Klo, Vthi, (float*)d_out);
}

// Round 5
// 166.360 us; speedup vs baseline: 2.1813x; 1.0903x over previous
//
#include <hip/hip_runtime.h>

typedef float f32x4 __attribute__((ext_vector_type(4)));
typedef __bf16 bf16x8 __attribute__((ext_vector_type(8)));
typedef unsigned short us8 __attribute__((ext_vector_type(8)));
typedef unsigned short us4 __attribute__((ext_vector_type(4)));

#define QSCALE 11.541560327111707f   // 8 * log2(e) -> softmax in exp2 domain
#define NEG_INF (-__builtin_inff())

__device__ __forceinline__ float fexp2(float x) {
    return __builtin_amdgcn_exp2f(x);
}
__device__ __forceinline__ unsigned short f2bf(float x) {   // round-nearest
    unsigned u = __builtin_bit_cast(unsigned, x);
    u += 0x7fffu + ((u >> 16) & 1u);
    return (unsigned short)(u >> 16);
}
__device__ __forceinline__ float bf2f(unsigned short h) {
    unsigned u = ((unsigned)h) << 16;
    return __builtin_bit_cast(float, u);
}
__device__ __forceinline__ unsigned short bftrunc(float x) { // truncate
    return (unsigned short)(__builtin_bit_cast(unsigned, x) >> 16);
}
__device__ __forceinline__ f32x4 mfma16(us8 a, us8 b, f32x4 c) {
    return __builtin_amdgcn_mfma_f32_16x16x32_bf16(
        __builtin_bit_cast(bf16x8, a), __builtin_bit_cast(bf16x8, b), c, 0, 0, 0);
}
__device__ __forceinline__ void glds16(const unsigned short* g, unsigned short* l) {
    __builtin_amdgcn_global_load_lds(
        (const __attribute__((address_space(1))) unsigned int*)g,
        (__attribute__((address_space(3))) unsigned int*)l, 16, 0, 0);
}

// ---------------- Kernel 0: W transpose + split (RN split) ----------------
__global__ __launch_bounds__(256) void wprep_kernel(
    const float* __restrict__ Wq, const float* __restrict__ Wk,
    const float* __restrict__ Wv,
    unsigned short* __restrict__ Wthi, unsigned short* __restrict__ Wtlo)
{
    __shared__ __align__(16) float Ls[64][68];
    const int g = blockIdx.x >> 4;
    const int k0 = (blockIdx.x & 15) << 6;
    const float* W = (g == 0) ? Wq : (g == 1) ? Wk : Wv;
    const int t = threadIdx.x;
#pragma unroll
    for (int u = 0; u < 4; ++u) {
        int idx = t + (u << 8);
        int row = idx >> 4, c4 = (idx & 15) << 2;
        *(float4*)&Ls[row][c4] = *(const float4*)&W[(size_t)(k0 + row) * 64 + c4];
    }
    __syncthreads();
    const int h = t >> 2, kk0 = (t & 3) << 4;
    size_t base = (size_t)((g << 6) + h) * 1024 + k0 + kk0;
#pragma unroll
    for (int c = 0; c < 4; ++c) {
        us4 hv, lv;
#pragma unroll
        for (int i = 0; i < 4; ++i) {
            float x = Ls[kk0 + (c << 2) + i][h];
            unsigned short hh = f2bf(x);
            hv[i] = hh;
            lv[i] = f2bf(x - bf2f(hh));
        }
        *(us4*)&Wthi[base + (c << 2)] = hv;
        *(us4*)&Wtlo[base + (c << 2)] = lv;
    }
}

// ---------------- Kernel 1: fused QKV projection ----------------
// 64x96 tile, grid (256,2) = 2 blocks/CU. K-step 64.
// X: fp32 global -> regs -> trunc-split -> swizzled LDS (converted ONCE/block).
// W-hi: double-buffered glds16.  W-lo: direct per-lane global frags (L2).
// Q written pre-scaled by 8*log2(e).
__global__ __launch_bounds__(256, 2) void qkv_kernel(
    const float* __restrict__ X,
    const unsigned short* __restrict__ Wthi,
    const unsigned short* __restrict__ Wtlo,
    unsigned short* __restrict__ Qhi, unsigned short* __restrict__ Qlo,
    unsigned short* __restrict__ Khi, unsigned short* __restrict__ Klo,
    unsigned short* __restrict__ Vthi)
{
    __shared__ __align__(16) unsigned short sm[21760];  // 42.5 KB
    unsigned short* Xh = sm;                 // 64x64, swizzled (4096)
    unsigned short* Xl = sm + 4096;          // 4096
    unsigned short* Wh = sm + 8192;          // 2 buf x 6144 (96x64 swizzled)
    unsigned short* Vx = sm + 20480;         // 4x16x20 transpose scratch

    const int t = threadIdx.x;
    const int w = t >> 6, l = t & 63, lm = l & 15, lg = (l >> 4) & 3;
    const int wq = w >> 1, wc = w & 1;
    const int m0 = blockIdx.x << 6;
    const int y  = blockIdx.y;

    // --- W-hi glds staging: 3 x 1KB per wave per iter (8 rows each) ---
    const unsigned short* gsrc[3];
    int gdst[3];
#pragma unroll
    for (int i = 0; i < 3; ++i) {
        int g = w * 3 + i;                      // 0..11
        int n = (g << 3) + (l >> 3);            // W row 0..95
        int cg = (l & 7) ^ ((l >> 3) & 7);      // swizzled source chunk
        gsrc[i] = Wthi + (size_t)(y * 96 + n) * 1024 + (cg << 3);
        gdst[i] = g << 9;                       // g*512 us
    }
    // --- X staging: thread -> 16 floats (row t>>2, k (t&3)*16..+16) ---
    const int xrow = t >> 2;
    const int xc0 = (t & 3) << 1;
    const float* xptr = X + (size_t)(m0 + xrow) * 1024 + ((t & 3) << 4);
    unsigned short* xwh0 = Xh + (xrow << 6) + ((xc0 ^ (xrow & 7)) << 3);
    unsigned short* xwh1 = Xh + (xrow << 6) + (((xc0 | 1) ^ (xrow & 7)) << 3);
    unsigned short* xwl0 = Xl + (xrow << 6) + ((xc0 ^ (xrow & 7)) << 3);
    unsigned short* xwl1 = Xl + (xrow << 6) + (((xc0 | 1) ^ (xrow & 7)) << 3);

    // --- fragment LDS offsets (swizzle: slot = (kc*4+lg) ^ (lm&7)) ---
    int aoff[2][2], boff[3][2];
#pragma unroll
    for (int rt = 0; rt < 2; ++rt)
#pragma unroll
        for (int kc = 0; kc < 2; ++kc) {
            int m = (wq << 5) + (rt << 4) + lm;
            aoff[rt][kc] = (m << 6) + ((((kc << 2) + lg) ^ (lm & 7)) << 3);
        }
#pragma unroll
    for (int ct = 0; ct < 3; ++ct)
#pragma unroll
        for (int kc = 0; kc < 2; ++kc) {
            int n = wc * 48 + (ct << 4) + lm;
            boff[ct][kc] = (n << 6) + ((((kc << 2) + lg) ^ (lm & 7)) << 3);
        }
    // --- W-lo direct global fragment pointers ---
    const unsigned short* wlp[3][2];
#pragma unroll
    for (int ct = 0; ct < 3; ++ct)
#pragma unroll
        for (int kc = 0; kc < 2; ++kc)
            wlp[ct][kc] = Wtlo + (size_t)(y * 96 + wc * 48 + (ct << 4) + lm) * 1024
                               + (kc << 5) + (lg << 3);

    f32x4 acc[2][3];
#pragma unroll
    for (int i = 0; i < 2; ++i)
#pragma unroll
        for (int j = 0; j < 3; ++j) acc[i][j] = (f32x4){0.f, 0.f, 0.f, 0.f};

    // prologue: W(0) -> buf0, X(0) -> regs
#pragma unroll
    for (int i = 0; i < 3; ++i) glds16(gsrc[i], Wh + gdst[i]);
    float4 xv[4];
#pragma unroll
    for (int i = 0; i < 4; ++i) xv[i] = *(const float4*)(xptr + (i << 2));

    for (int k = 0; k < 16; ++k) {
        const int wb = (k & 1) * 6144;
        __syncthreads();                                   // A: prev readers done
        if (k < 15) {
            const int ko = (k + 1) << 6;
            const int nb = 6144 - wb;
#pragma unroll
            for (int i = 0; i < 3; ++i) glds16(gsrc[i] + ko, Wh + nb + gdst[i]);
        }
        {   // convert X(k) (trunc split) and write swizzled LDS
            float xf[16];
#pragma unroll
            for (int i = 0; i < 4; ++i) {
                xf[4 * i] = xv[i].x; xf[4 * i + 1] = xv[i].y;
                xf[4 * i + 2] = xv[i].z; xf[4 * i + 3] = xv[i].w;
            }
            us8 h0, h1, lo0, lo1;
#pragma unroll
            for (int e = 0; e < 8; ++e) {
                unsigned u0 = __builtin_bit_cast(unsigned, xf[e]);
                h0[e] = (unsigned short)(u0 >> 16);
                lo0[e] = bftrunc(xf[e] - __builtin_bit_cast(float, u0 & 0xffff0000u));
                unsigned u1 = __builtin_bit_cast(unsigned, xf[e + 8]);
                h1[e] = (unsigned short)(u1 >> 16);
                lo1[e] = bftrunc(xf[e + 8] - __builtin_bit_cast(float, u1 & 0xffff0000u));
            }
            *(us8*)xwh0 = h0; *(us8*)xwh1 = h1;
            *(us8*)xwl0 = lo0; *(us8*)xwl1 = lo1;
        }
        __syncthreads();                                   // B: stage visible
        if (k < 15) {
            const int ko = (k + 1) << 6;
#pragma unroll
            for (int i = 0; i < 4; ++i)
                xv[i] = *(const float4*)(xptr + ko + (i << 2));
        }
        us8 bl[3][2];
#pragma unroll
        for (int ct = 0; ct < 3; ++ct)
#pragma unroll
            for (int kc = 0; kc < 2; ++kc)
                bl[ct][kc] = *(const us8*)(wlp[ct][kc] + (k << 6));
        us8 ah[2][2], al[2][2], bh[3][2];
#pragma unroll
        for (int rt = 0; rt < 2; ++rt)
#pragma unroll
            for (int kc = 0; kc < 2; ++kc) {
                ah[rt][kc] = *(const us8*)&Xh[aoff[rt][kc]];
                al[rt][kc] = *(const us8*)&Xl[aoff[rt][kc]];
            }
#pragma unroll
        for (int ct = 0; ct < 3; ++ct)
#pragma unroll
            for (int kc = 0; kc < 2; ++kc)
                bh[ct][kc] = *(const us8*)&Wh[wb + boff[ct][kc]];
        // LDS-only terms first (hi*hi, lo*hi), then terms needing W-lo globals
#pragma unroll
        for (int kc = 0; kc < 2; ++kc)
#pragma unroll
            for (int rt = 0; rt < 2; ++rt)
#pragma unroll
                for (int ct = 0; ct < 3; ++ct) {
                    acc[rt][ct] = mfma16(ah[rt][kc], bh[ct][kc], acc[rt][ct]);
                    acc[rt][ct] = mfma16(al[rt][kc], bh[ct][kc], acc[rt][ct]);
                }
#pragma unroll
        for (int kc = 0; kc < 2; ++kc)
#pragma unroll
            for (int rt = 0; rt < 2; ++rt)
#pragma unroll
                for (int ct = 0; ct < 3; ++ct)
                    acc[rt][ct] = mfma16(ah[rt][kc], bl[ct][kc], acc[rt][ct]);
    }

    // epilogue: trunc-split stores; Q pre-scaled; V transposed via Vx
    const int tbr = m0 + (wq << 5);
#pragma unroll
    for (int rt = 0; rt < 2; ++rt) {
#pragma unroll
        for (int ct = 0; ct < 3; ++ct) {
            const int gc = y * 96 + wc * 48 + (ct << 4);
            if (gc < 128) {
                unsigned short* Dh = (gc < 64) ? Qhi : Khi;
                unsigned short* Dl = (gc < 64) ? Qlo : Klo;
                const float sc = (gc < 64) ? QSCALE : 1.0f;
                const int colb = (gc & 63) + lm;
#pragma unroll
                for (int r = 0; r < 4; ++r) {
                    int row = tbr + (rt << 4) + (lg << 2) + r;
                    float x = acc[rt][ct][r] * sc;
                    unsigned u = __builtin_bit_cast(unsigned, x);
                    size_t o = (size_t)row * 64 + colb;
                    Dh[o] = (unsigned short)(u >> 16);
                    Dl[o] = bftrunc(x - __builtin_bit_cast(float, u & 0xffff0000u));
                }
            } else {
                // V: 16x16 transpose via wave-local LDS
#pragma unroll
                for (int r = 0; r < 4; ++r)
                    Vx[w * 320 + lm * 20 + (lg << 2) + r] = bftrunc(acc[rt][ct][r]);
                __asm__ volatile("" ::: "memory");
                const int h0 = gc - 128;
                const int tb = tbr + (rt << 4);
                const int bb = tb >> 11;
                const int tl = (tb & 2047) + ((l & 3) << 2);
                const int hh2 = h0 + (l >> 2);
                us4 vv = *(const us4*)&Vx[w * 320 + (l >> 2) * 20 + ((l & 3) << 2)];
                *(us4*)&Vthi[(size_t)((bb << 6) + hh2) * 2048 + tl] = vv;
                __asm__ volatile("" ::: "memory");
            }
        }
    }
}

// ---------------- Kernel 2: causal flash attention ----------------
// 512 blocks = (b, 32-row q-tile, heavy-first). 4 waves = 4 key-parities,
// ZERO barriers in the K-loop (K/V frags direct from global, L2-resident).
// S^T layout: lane = q-row -> softmax reduce = 15 local ops + 2 shuffles.
// exp2 domain (Q pre-scaled by 8*log2e). 4-way merge at end.
__global__ __launch_bounds__(256, 2) void attn_kernel(
    const unsigned short* __restrict__ Qhi, const unsigned short* __restrict__ Qlo,
    const unsigned short* __restrict__ Khi, const unsigned short* __restrict__ Klo,
    const unsigned short* __restrict__ Vthi,
    float* __restrict__ O)
{
    __shared__ __align__(16) unsigned char smem[33792];
    unsigned short* PS = (unsigned short*)smem;     // [4][32][72] us (loop phase)
    float* FO = (float*)smem;                       // [4][32][64] f32 (merge phase)
    float* FM = (float*)(smem + 32768);             // [4][32]
    float* FL = FM + 128;

    const int t = threadIdx.x;
    const int w = t >> 6, l = t & 63, lm = l & 15, lg = (l >> 4) & 3;
    const int b = blockIdx.x & 7;
    const int qp = 63 - (blockIdx.x >> 3);          // heavy tiles first
    const int nk = (qp >> 1) + 1;                   // 64-key tiles needed
    const int q0 = qp << 5;
    const size_t brow = (size_t)b << 11;

    // Q fragments pinned (B-operand: lane=qrow, k=lg*8+j)
    us8 qh[2][2], ql[2][2];
#pragma unroll
    for (int nt = 0; nt < 2; ++nt)
#pragma unroll
        for (int kc = 0; kc < 2; ++kc) {
            size_t off = (brow + q0 + (nt << 4) + lm) * 64 + (kc << 5) + (lg << 3);
            qh[nt][kc] = *(const us8*)&Qhi[off];
            ql[nt][kc] = *(const us8*)&Qlo[off];
        }

    f32x4 o_acc[2][4];
#pragma unroll
    for (int nt = 0; nt < 2; ++nt)
#pragma unroll
        for (int ct = 0; ct < 4; ++ct) o_acc[nt][ct] = (f32x4){0.f, 0.f, 0.f, 0.f};
    float m_r[2] = {NEG_INF, NEG_INF}, l_r[2] = {0.f, 0.f};
    unsigned short* ps = PS + w * 2304;             // wave-local 32x72

    for (int j = w; j < nk; j += 4) {
        const int kk0 = j << 6;
        us8 kh[4][2], klo[4][2], vh[4][2];
#pragma unroll
        for (int mt = 0; mt < 4; ++mt)
#pragma unroll
            for (int kc = 0; kc < 2; ++kc) {
                size_t off = (brow + kk0 + (mt << 4) + lm) * 64 + (kc << 5) + (lg << 3);
                kh[mt][kc] = *(const us8*)&Khi[off];
                klo[mt][kc] = *(const us8*)&Klo[off];
            }
#pragma unroll
        for (int ct = 0; ct < 4; ++ct)
#pragma unroll
            for (int kc = 0; kc < 2; ++kc) {
                size_t off = ((size_t)(b << 6) + (ct << 4) + lm) * 2048
                           + kk0 + (kc << 5) + (lg << 3);
                vh[ct][kc] = *(const us8*)&Vthi[off];
            }
        // S^T = K Q^T (split-bf16)
        f32x4 s[4][2];
#pragma unroll
        for (int mt = 0; mt < 4; ++mt)
#pragma unroll
            for (int nt = 0; nt < 2; ++nt) s[mt][nt] = (f32x4){0.f, 0.f, 0.f, 0.f};
#pragma unroll
        for (int kc = 0; kc < 2; ++kc)
#pragma unroll
            for (int mt = 0; mt < 4; ++mt)
#pragma unroll
                for (int nt = 0; nt < 2; ++nt) {
                    s[mt][nt] = mfma16(kh[mt][kc], qh[nt][kc], s[mt][nt]);
                    s[mt][nt] = mfma16(klo[mt][kc], qh[nt][kc], s[mt][nt]);
                    s[mt][nt] = mfma16(kh[mt][kc], ql[nt][kc], s[mt][nt]);
                }
        // online softmax (exp2 domain), lane owns row q0+nt*16+lm, 16 keys
        float alz[2];
#pragma unroll
        for (int nt = 0; nt < 2; ++nt) {
            const int qr = q0 + (nt << 4) + lm;
            float sv[16];
            if ((kk0 + 63) <= (q0 + (nt << 4))) {
#pragma unroll
                for (int mt = 0; mt < 4; ++mt)
#pragma unroll
                    for (int r = 0; r < 4; ++r) sv[(mt << 2) + r] = s[mt][nt][r];
            } else {
#pragma unroll
                for (int mt = 0; mt < 4; ++mt)
#pragma unroll
                    for (int r = 0; r < 4; ++r) {
                        const int key = kk0 + (mt << 4) + (lg << 2) + r;
                        sv[(mt << 2) + r] = (key <= qr) ? s[mt][nt][r] : NEG_INF;
                    }
            }
            float t8[8];
#pragma unroll
            for (int i = 0; i < 8; ++i) t8[i] = fmaxf(sv[i], sv[i + 8]);
#pragma unroll
            for (int i = 0; i < 4; ++i) t8[i] = fmaxf(t8[i], t8[i + 4]);
            float mx = fmaxf(fmaxf(t8[0], t8[1]), fmaxf(t8[2], t8[3]));
            mx = fmaxf(mx, __shfl_xor(mx, 16));
            mx = fmaxf(mx, __shfl_xor(mx, 32));
            const float mn = fmaxf(m_r[nt], mx);
            alz[nt] = fexp2(m_r[nt] - mn);
            m_r[nt] = mn;
            float p[16];
#pragma unroll
            for (int i = 0; i < 16; ++i) p[i] = fexp2(sv[i] - mn);
#pragma unroll
            for (int mt = 0; mt < 4; ++mt) {
                us4 pk;
#pragma unroll
                for (int r = 0; r < 4; ++r) pk[r] = bftrunc(p[(mt << 2) + r]);
                *(us4*)&ps[((nt << 4) + lm) * 72 + (mt << 4) + (lg << 2)] = pk;
            }
            float s8[8];
#pragma unroll
            for (int i = 0; i < 8; ++i) s8[i] = p[i] + p[i + 8];
#pragma unroll
            for (int i = 0; i < 4; ++i) s8[i] = s8[i] + s8[i + 4];
            float rs = (s8[0] + s8[1]) + (s8[2] + s8[3]);
            rs += __shfl_xor(rs, 16);
            rs += __shfl_xor(rs, 32);
            l_r[nt] = l_r[nt] * alz[nt] + rs;
        }
        __asm__ volatile("" ::: "memory");   // P write -> read, same wave
        // rescale O (alz lives at lane=row; fetch via shuffle)
#pragma unroll
        for (int nt = 0; nt < 2; ++nt)
#pragma unroll
            for (int r = 0; r < 4; ++r) {
                const float av = __shfl(alz[nt], (lg << 2) + r);
#pragma unroll
                for (int ct = 0; ct < 4; ++ct) o_acc[nt][ct][r] *= av;
            }
        // O += P V
#pragma unroll
        for (int nt = 0; nt < 2; ++nt)
#pragma unroll
            for (int kc = 0; kc < 2; ++kc) {
                us8 pa = *(const us8*)&ps[((nt << 4) + lm) * 72 + (kc << 5) + (lg << 3)];
#pragma unroll
                for (int ct = 0; ct < 4; ++ct)
                    o_acc[nt][ct] = mfma16(pa, vh[ct][kc], o_acc[nt][ct]);
            }
    }

    // ---- 4-way key-parity merge ----
    __syncthreads();                         // all PS use done before FO alias
#pragma unroll
    for (int nt = 0; nt < 2; ++nt)
#pragma unroll
        for (int ct = 0; ct < 4; ++ct)
#pragma unroll
            for (int r = 0; r < 4; ++r)
                FO[(w << 11) + (((nt << 4) + (lg << 2) + r) << 6) + (ct << 4) + lm]
                    = o_acc[nt][ct][r];
    if (l < 16) {
        FM[(w << 5) + lm] = m_r[0]; FM[(w << 5) + 16 + lm] = m_r[1];
        FL[(w << 5) + lm] = l_r[0]; FL[(w << 5) + 16 + lm] = l_r[1];
    }
    __syncthreads();
    const int jr = t >> 3;                   // row 0..31
    const int cg = (t & 7) << 3;             // col base
    float m0v = FM[jr], m1v = FM[32 + jr], m2v = FM[64 + jr], m3v = FM[96 + jr];
    float mm = fmaxf(fmaxf(m0v, m1v), fmaxf(m2v, m3v));
    float a0 = fexp2(m0v - mm), a1 = fexp2(m1v - mm);
    float a2 = fexp2(m2v - mm), a3 = fexp2(m3v - mm);
    float L = a0 * FL[jr] + a1 * FL[32 + jr] + a2 * FL[64 + jr] + a3 * FL[96 + jr];
    float inv = 1.0f / L;
    float ov[8];
#pragma unroll
    for (int c = 0; c < 8; ++c)
        ov[c] = a0 * FO[(jr << 6) + cg + c] + a1 * FO[2048 + (jr << 6) + cg + c]
              + a2 * FO[4096 + (jr << 6) + cg + c] + a3 * FO[6144 + (jr << 6) + cg + c];
    float4 o1 = {ov[0] * inv, ov[1] * inv, ov[2] * inv, ov[3] * inv};
    float4 o2 = {ov[4] * inv, ov[5] * inv, ov[6] * inv, ov[7] * inv};
    float* op = O + (brow + q0 + jr) * 64 + cg;
    *(float4*)op = o1;
    *(float4*)(op + 4) = o2;
}

extern "C" void kernel_launch(void* const* d_in, const int* in_sizes, int n_in,
                              void* d_out, int out_size, void* d_ws, size_t ws_size,
                              hipStream_t stream) {
    const float* X  = (const float*)d_in[0];
    const float* Wq = (const float*)d_in[1];
    const float* Wk = (const float*)d_in[2];
    const float* Wv = (const float*)d_in[3];
    unsigned short* ws = (unsigned short*)d_ws;
    const size_t SZ = (size_t)16384 * 64;
    unsigned short* Qhi  = ws;
    unsigned short* Qlo  = ws + SZ;
    unsigned short* Khi  = ws + 2 * SZ;
    unsigned short* Klo  = ws + 3 * SZ;
    unsigned short* Vthi = ws + 4 * SZ;
    unsigned short* Wthi = ws + 5 * SZ;
    unsigned short* Wtlo = Wthi + 192 * 1024;

    wprep_kernel<<<48, 256, 0, stream>>>(Wq, Wk, Wv, Wthi, Wtlo);
    qkv_kernel<<<dim3(256, 2), 256, 0, stream>>>(X, Wthi, Wtlo,
                                                 Qhi, Qlo, Khi, Klo, Vthi);
    attn_kernel<<<512, 256, 0, stream>>>(Qhi, Qlo, Khi, Klo, Vthi, (float*)d_out);
}